// Round 4
// baseline (232.182 us; speedup 1.0000x reference)
//
#include <hip/hip_runtime.h>
#include <hip/hip_fp16.h>

// GCN tail: 2×(GCNConv+ReLU) + linear head.  N=100000, E=1000000, F_in=128, H=64, C=40.
//
// R13: fuse gather_i + gemm_(i+1) into one kernel (gather rows -> LDS ->
// block-local MFMA). Legal because gemm_(i+1) only needs the 64 rows this
// block gathered; the cross-block dependency stays at the gemm_i boundary.
//  - eliminates 2×12.8MB intermediate round-trips + 2 launches
//  - W split hi/lo staged at kernel top (L2-hot loads finish under gather)
//  - bit-identical accumulation/rounding vs R12 -> absmax must not move
//  - fused kernels likely >41us -> visible in rocprof top-5 (diagnostic)
// Pipeline: zero, bucket_fill, node_sort, gemm1, fused1(gather+W2), fused2(gather+Wc).

#define BUCKET_BITS  8
#define BUCKET_NODES 256
#define MAXB 512            // max buckets supported (N <= 131072)
#define CAP  8192           // slots per bucket window (Binom(1M,1/391)=2558±51)
#define OFF_MASK 0x3FFFFF   // 22 bits

typedef _Float16 half8 __attribute__((ext_vector_type(8)));
typedef float    f32x4 __attribute__((ext_vector_type(4)));

union H8  { uint4 u; __half h[8]; };
union HV8 { uint4 u; half8 h; };

__global__ void zero_kernel(int* __restrict__ p, int n) {
    int i = blockIdx.x * blockDim.x + threadIdx.x;
    if (i < n) p[i] = 0;
}

// Single-pass counting-sort fill into fixed-capacity bucket windows.
// entry = (dstLocal<<24) | src   (src < 2^24)
__global__ __launch_bounds__(256) void bucket_fill_kernel(const int* __restrict__ src,
                                                          const int* __restrict__ dst,
                                                          int* __restrict__ bucketCursor,
                                                          unsigned int* __restrict__ bucketArr,
                                                          int E, int NB) {
    __shared__ int lcnt[MAXB];
    __shared__ int dcache[4096];
    for (int i = threadIdx.x; i < NB; i += 256) lcnt[i] = 0;
    __syncthreads();
    const int base = blockIdx.x * 4096;
#pragma unroll
    for (int k = 0; k < 16; ++k) {
        int idx = k * 256 + threadIdx.x;
        int e = base + idx;
        if (e < E) {
            int d = dst[e];
            dcache[idx] = d;
            atomicAdd(&lcnt[d >> BUCKET_BITS], 1);
        }
    }
    __syncthreads();
    for (int i = threadIdx.x; i < NB; i += 256) {
        int c = lcnt[i];
        if (c) lcnt[i] = i * CAP + atomicAdd(&bucketCursor[i], c);  // count -> abs base
    }
    __syncthreads();
#pragma unroll
    for (int k = 0; k < 16; ++k) {
        int idx = k * 256 + threadIdx.x;
        int e = base + idx;
        if (e < E) {
            int d = dcache[idx];
            int s = src[e];
            int pos = atomicAdd(&lcnt[d >> BUCKET_BITS], 1);
            bucketArr[pos] = ((unsigned)(d & (BUCKET_NODES - 1)) << 24) | (unsigned)s;
        }
    }
}

// Per bucket: count -> scan -> nodeInfo=(cnt<<22)|absOff + dinv, then scatter
// src-only adj entries via LDS cursors. Window read twice but L2-hot.
__global__ __launch_bounds__(256) void node_sort_kernel(const unsigned int* __restrict__ bucketArr,
                                                        const int* __restrict__ bucketCursor,
                                                        unsigned int* __restrict__ nodeInfo,
                                                        float* __restrict__ dinv,
                                                        unsigned int* __restrict__ adj, int N) {
    __shared__ int cnt[BUCKET_NODES];
    __shared__ int scn[BUCKET_NODES];
    __shared__ int cur[BUCKET_NODES];
    const int t = threadIdx.x;
    const int b = blockIdx.x;
    cnt[t] = 0;
    __syncthreads();
    const int e0 = b * CAP;
    const int e1 = e0 + bucketCursor[b];
    for (int e = e0 + t; e < e1; e += 256)
        atomicAdd(&cnt[bucketArr[e] >> 24], 1);
    __syncthreads();
    int v = cnt[t];
    scn[t] = v;
    __syncthreads();
    for (int off = 1; off < 256; off <<= 1) {
        int u = (t >= off) ? scn[t - off] : 0;
        __syncthreads();
        scn[t] += u;
        __syncthreads();
    }
    const int excl = scn[t] - v;
    const int node = b * BUCKET_NODES + t;
    if (node < N) {
        nodeInfo[node] = ((unsigned)v << 22) | (unsigned)(e0 + excl);
        dinv[node]     = rsqrtf((float)(v + 1));
    }
    cur[t] = e0 + excl;
    __syncthreads();
    for (int e = e0 + t; e < e1; e += 256) {
        unsigned int entry = bucketArr[e];
        int pos = atomicAdd(&cur[entry >> 24], 1);
        adj[pos] = entry & 0xFFFFFF;
    }
}

// ---- MFMA GEMM (layer 1 only): out = (A[M,128] @ W1[128,64]) * dinv -------
// Self-contained: W split hi/lo fp16 + transposed into LDS per block.
template <int K, int NOUT, int NCT, bool AHALF, bool OHALF, bool SCALE, bool BIAS>
__global__ __launch_bounds__(256) void gemm_mfma(const void* __restrict__ Av,
                                                 const float* __restrict__ W,
                                                 const float* __restrict__ bias,
                                                 const float* __restrict__ dscale,
                                                 void* __restrict__ outv, int M) {
    constexpr int KP = K + 8;                 // +16B row pad: 2-way bank floor
    __shared__ _Float16 WTh[64 * KP];
    __shared__ _Float16 WTl[64 * KP];

    for (int i = threadIdx.x; i < K * 64; i += 256) {
        int k = i >> 6, c = i & 63;
        float w = (NOUT == 64 || c < NOUT) ? W[k * NOUT + c] : 0.f;
        _Float16 h = (_Float16)w;
        WTh[c * KP + k] = h;
        WTl[c * KP + k] = (_Float16)(w - (float)h);
    }
    __syncthreads();

    const int lane = threadIdx.x & 63;
    const int wv   = threadIdx.x >> 6;
    const int r    = lane & 15;   // A-row / D-col within 16-tile
    const int q    = lane >> 4;   // k-group / D-row-group
    int arow = blockIdx.x * 64 + wv * 16 + r;
    if (arow > M - 1) arow = M - 1;

    f32x4 acc[NCT] = {};

#pragma unroll
    for (int kst = 0; kst < K; kst += 32) {
        half8 ah = {}, al = {};
        if (AHALF) {
            HV8 v;
            v.u = *(const uint4*)((const __half*)Av + (size_t)arow * K + kst + q * 8);
            ah = v.h;
        } else {
            const float* ap = (const float*)Av + (size_t)arow * K + kst + q * 8;
            float4 f0 = *(const float4*)ap;
            float4 f1 = *(const float4*)(ap + 4);
            float fs[8] = {f0.x, f0.y, f0.z, f0.w, f1.x, f1.y, f1.z, f1.w};
#pragma unroll
            for (int j = 0; j < 8; ++j) {
                _Float16 h = (_Float16)fs[j];
                ah[j] = h;
                al[j] = (_Float16)(fs[j] - (float)h);
            }
        }
#pragma unroll
        for (int n = 0; n < NCT; ++n) {
            const int bo = (n * 16 + r) * KP + kst + q * 8;
            HV8 bh, bl;
            bh.u = *(const uint4*)(WTh + bo);
            bl.u = *(const uint4*)(WTl + bo);
            acc[n] = __builtin_amdgcn_mfma_f32_16x16x32_f16(ah, bh.h, acc[n], 0, 0, 0);
            acc[n] = __builtin_amdgcn_mfma_f32_16x16x32_f16(ah, bl.h, acc[n], 0, 0, 0);
            if (!AHALF)
                acc[n] = __builtin_amdgcn_mfma_f32_16x16x32_f16(al, bh.h, acc[n], 0, 0, 0);
        }
    }

    const int orow0 = blockIdx.x * 64 + wv * 16 + q * 4;
#pragma unroll
    for (int n = 0; n < NCT; ++n) {
        const int col = n * 16 + r;
        float bb = 0.f;
        if (BIAS) bb = (col < NOUT) ? bias[col] : 0.f;
#pragma unroll
        for (int j = 0; j < 4; ++j) {
            const int row = orow0 + j;
            if (row >= M) break;
            const float sc = SCALE ? dscale[row] : 1.f;
            const float v = acc[n][j] * sc + bb;
            if (OHALF) {
                ((__half*)outv)[(size_t)row * NOUT + col] = __float2half(v);
            } else if (col < NOUT) {
                ((float*)outv)[(size_t)row * NOUT + col] = v;
            }
        }
    }
}

// ---- fused gather + GEMM ---------------------------------------------------
// Phase A (gather): 64 nodes/block, eighth-wave; each eighth handles local
// rows E8 and E8+32. h1row = relu(dinv*(h'[n] + sum h'[s]) + gbias), written
// to LDS At[64][72] fp16 (144B stride -> free 2-way bank aliasing).
// Phase B (MFMA): out = (At @ W) [* dinv] [+ obias]; W split hi/lo staged at
// kernel top so its L2-hot loads complete under the gather latency.
template <int NOUT, int NCT, bool OHALF, bool SCALE, bool OBIAS>
__global__ __launch_bounds__(256) void gather_gemm(const __half* __restrict__ h,
                                                   const unsigned int* __restrict__ nodeInfo,
                                                   const unsigned int* __restrict__ adj,
                                                   const float* __restrict__ dinv,
                                                   const float* __restrict__ gbias,
                                                   const float* __restrict__ W,
                                                   const float* __restrict__ obias,
                                                   void* __restrict__ outv, int N) {
    constexpr int KP = 72;                    // 64 + 8 halves pad
    __shared__ _Float16 At[64 * KP];
    __shared__ _Float16 WTh[64 * KP];
    __shared__ _Float16 WTl[64 * KP];

    // stage W split (issue early; completes under gather)
    for (int i = threadIdx.x; i < 64 * 64; i += 256) {
        int k = i >> 6, c = i & 63;
        float w = (NOUT == 64 || c < NOUT) ? W[k * NOUT + c] : 0.f;
        _Float16 hh = (_Float16)w;
        WTh[c * KP + k] = hh;
        WTl[c * KP + k] = (_Float16)(w - (float)hh);
    }

    const int row0 = blockIdx.x * 64;
    const int E8   = threadIdx.x >> 3;        // eighth 0..31
    const int l    = threadIdx.x & 7;         // lane within eighth

    const float4 g0 = *(const float4*)(gbias + l * 8);
    const float4 g1 = *(const float4*)(gbias + l * 8 + 4);
    const float gb[8] = {g0.x, g0.y, g0.z, g0.w, g1.x, g1.y, g1.z, g1.w};

#pragma unroll
    for (int half = 0; half < 2; ++half) {
        const int lr = E8 + half * 32;        // local row 0..63
        int node = row0 + lr;
        if (node > N - 1) node = N - 1;       // clamped dup rows never stored
        const unsigned info = nodeInfo[node];
        const int start = (int)(info & OFF_MASK);
        const int end   = start + (int)(info >> 22);
        const float di  = dinv[node];

        float acc[8];
        {
            H8 sv;
            sv.u = *(const uint4*)(h + (size_t)node * 64 + l * 8);
#pragma unroll
            for (int k = 0; k < 8; ++k) acc[k] = __half2float(sv.h[k]);
        }
        for (int base = start; base < end; base += 8) {
            const int m = min(8, end - base);
            int idx[8];
#pragma unroll
            for (int j = 0; j < 8; ++j) idx[j] = (int)adj[base + j];  // bounded by CAP slack
#pragma unroll
            for (int j = 0; j < 8; ++j)
                if (j < m) {
                    H8 rv;
                    rv.u = *(const uint4*)(h + (size_t)idx[j] * 64 + l * 8);
#pragma unroll
                    for (int k = 0; k < 8; ++k) acc[k] += __half2float(rv.h[k]);
                }
        }
        H8 ov;
#pragma unroll
        for (int k = 0; k < 8; ++k) {
            float v = acc[k] * di + gb[k];
            ov.h[k] = __float2half(v > 0.f ? v : 0.f);
        }
        *(uint4*)(&At[lr * KP + l * 8]) = ov.u;
    }
    __syncthreads();

    // ---- MFMA phase: 4 waves x 16 rows ----
    const int lane = threadIdx.x & 63;
    const int wv   = threadIdx.x >> 6;
    const int r    = lane & 15;
    const int q    = lane >> 4;

    f32x4 acc2[NCT] = {};
#pragma unroll
    for (int kst = 0; kst < 64; kst += 32) {
        HV8 av;
        av.u = *(const uint4*)(&At[(wv * 16 + r) * KP + kst + q * 8]);
#pragma unroll
        for (int n = 0; n < NCT; ++n) {
            const int bo = (n * 16 + r) * KP + kst + q * 8;
            HV8 bh, bl;
            bh.u = *(const uint4*)(&WTh[bo]);
            bl.u = *(const uint4*)(&WTl[bo]);
            acc2[n] = __builtin_amdgcn_mfma_f32_16x16x32_f16(av.h, bh.h, acc2[n], 0, 0, 0);
            acc2[n] = __builtin_amdgcn_mfma_f32_16x16x32_f16(av.h, bl.h, acc2[n], 0, 0, 0);
        }
    }

    const int orow0 = row0 + wv * 16 + q * 4;
#pragma unroll
    for (int n = 0; n < NCT; ++n) {
        const int col = n * 16 + r;
        float bb = 0.f;
        if (OBIAS) bb = (col < NOUT) ? obias[col] : 0.f;
#pragma unroll
        for (int j = 0; j < 4; ++j) {
            const int row = orow0 + j;
            if (row >= N) break;
            const float sc = SCALE ? dinv[row] : 1.f;
            const float v = acc2[n][j] * sc + bb;
            if (OHALF) {
                ((__half*)outv)[(size_t)row * NOUT + col] = __float2half(v);
            } else if (col < NOUT) {
                ((float*)outv)[(size_t)row * NOUT + col] = v;
            }
        }
    }
}

extern "C" void kernel_launch(void* const* d_in, const int* in_sizes, int n_in,
                              void* d_out, int out_size, void* d_ws, size_t ws_size,
                              hipStream_t stream) {
    const float* x  = (const float*)d_in[0];
    const int*   ei = (const int*)d_in[1];
    const float* W1 = (const float*)d_in[2];
    const float* b1 = (const float*)d_in[3];
    const float* W2 = (const float*)d_in[4];
    const float* b2 = (const float*)d_in[5];
    const float* Wc = (const float*)d_in[6];
    const float* bc = (const float*)d_in[7];

    const int N = in_sizes[0] / 128;   // 100000
    const int E = in_sizes[1] / 2;     // 1000000
    const int* src = ei;
    const int* dst = ei + E;

    const int NB = (N + BUCKET_NODES - 1) >> BUCKET_BITS;   // 391
    const int EB = (E + 4095) / 4096;                        // 245

    char* w = (char*)d_ws;
    auto alloc = [&](size_t bytes) { char* p = w; w += (bytes + 255) & ~(size_t)255; return p; };
    int*          bucketCursor = (int*)alloc((size_t)NB * 4);
    unsigned int* bucketArr    = (unsigned int*)alloc((size_t)NB * CAP * 4);
    unsigned int* nodeInfo     = (unsigned int*)alloc((size_t)N * 4);
    unsigned int* adj          = (unsigned int*)alloc((size_t)NB * CAP * 4);
    float*        dinv         = (float*)alloc((size_t)N * 4);
    __half*       bufA         = (__half*)alloc((size_t)N * 64 * 2);
    __half*       bufB         = (__half*)alloc((size_t)N * 64 * 2);

    dim3 blk(256);
    const int nblkG = (N + 63) / 64;   // 64 rows/nodes per block

    // ---- bucket build (3 launches) ----
    zero_kernel<<<(NB + 255) / 256, blk, 0, stream>>>(bucketCursor, NB);
    bucket_fill_kernel<<<EB, blk, 0, stream>>>(src, dst, bucketCursor, bucketArr, E, NB);
    node_sort_kernel<<<NB, blk, 0, stream>>>(bucketArr, bucketCursor, nodeInfo, dinv, adj, N);

    // ---- layer 1 GEMM:  bufA = (x @ W1) * dinv[row] ----
    gemm_mfma<128, 64, 4, false, true, true, false><<<nblkG, blk, 0, stream>>>(
        x, W1, nullptr, dinv, bufA, N);

    // ---- fused: gather(bufA)+b1+relu -> @W2 *dinv -> bufB ----
    gather_gemm<64, 4, true, true, false><<<nblkG, blk, 0, stream>>>(
        bufA, nodeInfo, adj, dinv, b1, W2, nullptr, bufB, N);

    // ---- fused: gather(bufB)+b2+relu -> @Wc +bc -> d_out ----
    gather_gemm<40, 3, false, false, true><<<nblkG, blk, 0, stream>>>(
        bufB, nodeInfo, adj, dinv, b2, Wc, bc, d_out, N);
}

// Round 5
// 219.416 us; speedup vs baseline: 1.0582x; 1.0582x over previous
//
#include <hip/hip_runtime.h>
#include <hip/hip_fp16.h>

// GCN tail: 2×(GCNConv+ReLU) + linear head.  N=100000, E=1000000, F_in=128, H=64, C=40.
//
// R14: unfuse (back to R12 pipeline, best measured) + de-starve the build grid.
//  - R13 counters: fused gather_gemm 48us each, ALL utilizations low, occ 30%
//    -> fusion reverted. Budget says ~110us hides in fill+sort: fill ran 245
//    blocks on 256 CUs (sub-1 block/CU!), sort 391x4 waves on 1024 SIMDs.
//  - bucket_fill: 2048-edge chunks (489 blocks), (dst,src) held in regs across
//    both phases (no dcache LDS, single pass over memory).
//  - node_sort: 1024 threads/block -> 2.5 strided iterations instead of 10;
//    scan on first 256 threads.
//  - Edge order within buckets changes -> gather sum order permutes; absmax
//    may move ~1e-3 (threshold 4.5e-2). All compute kernels identical to R12.

#define BUCKET_BITS  8
#define BUCKET_NODES 256
#define MAXB 512            // max buckets supported (N <= 131072)
#define CAP  8192           // slots per bucket window (Binom(1M,1/391)=2558±51)
#define OFF_MASK 0x3FFFFF   // 22 bits

typedef _Float16 half8 __attribute__((ext_vector_type(8)));
typedef float    f32x4 __attribute__((ext_vector_type(4)));

union H8  { uint4 u; __half h[8]; };
union HV8 { uint4 u; half8 h; };

__global__ void zero_kernel(int* __restrict__ p, int n) {
    int i = blockIdx.x * blockDim.x + threadIdx.x;
    if (i < n) p[i] = 0;
}

// Single-pass counting-sort fill into fixed-capacity bucket windows.
// entry = (dstLocal<<24) | src   (src < 2^24)
// R14: 2048-edge chunks, 8 edges/thread held in registers across both phases.
__global__ __launch_bounds__(256) void bucket_fill_kernel(const int* __restrict__ src,
                                                          const int* __restrict__ dst,
                                                          int* __restrict__ bucketCursor,
                                                          unsigned int* __restrict__ bucketArr,
                                                          int E, int NB) {
    __shared__ int lcnt[MAXB];
    for (int i = threadIdx.x; i < NB; i += 256) lcnt[i] = 0;
    __syncthreads();
    const int base = blockIdx.x * 2048;
    int d[8], s[8];
#pragma unroll
    for (int k = 0; k < 8; ++k) {
        int e = base + k * 256 + threadIdx.x;
        bool ok = e < E;
        d[k] = ok ? dst[e] : -1;
        s[k] = ok ? src[e] : 0;
    }
#pragma unroll
    for (int k = 0; k < 8; ++k)
        if (d[k] >= 0) atomicAdd(&lcnt[d[k] >> BUCKET_BITS], 1);
    __syncthreads();
    for (int i = threadIdx.x; i < NB; i += 256) {
        int c = lcnt[i];
        if (c) lcnt[i] = i * CAP + atomicAdd(&bucketCursor[i], c);  // count -> abs base
    }
    __syncthreads();
#pragma unroll
    for (int k = 0; k < 8; ++k)
        if (d[k] >= 0) {
            int pos = atomicAdd(&lcnt[d[k] >> BUCKET_BITS], 1);
            bucketArr[pos] = ((unsigned)(d[k] & (BUCKET_NODES - 1)) << 24) | (unsigned)s[k];
        }
}

// Per bucket: count -> scan -> nodeInfo=(cnt<<22)|absOff + dinv, then scatter
// src-only adj entries via LDS cursors. R14: 1024 threads/block (16 waves).
__global__ __launch_bounds__(1024) void node_sort_kernel(const unsigned int* __restrict__ bucketArr,
                                                         const int* __restrict__ bucketCursor,
                                                         unsigned int* __restrict__ nodeInfo,
                                                         float* __restrict__ dinv,
                                                         unsigned int* __restrict__ adj, int N) {
    __shared__ int cnt[BUCKET_NODES];
    __shared__ int scn[BUCKET_NODES];
    __shared__ int cur[BUCKET_NODES];
    const int t = threadIdx.x;
    const int b = blockIdx.x;
    if (t < BUCKET_NODES) cnt[t] = 0;
    __syncthreads();
    const int e0 = b * CAP;
    const int e1 = e0 + bucketCursor[b];
    for (int e = e0 + t; e < e1; e += 1024)
        atomicAdd(&cnt[bucketArr[e] >> 24], 1);
    __syncthreads();
    if (t < BUCKET_NODES) scn[t] = cnt[t];
    __syncthreads();
    for (int off = 1; off < BUCKET_NODES; off <<= 1) {
        int u = 0;
        if (t < BUCKET_NODES && t >= off) u = scn[t - off];
        __syncthreads();
        if (t < BUCKET_NODES) scn[t] += u;
        __syncthreads();
    }
    if (t < BUCKET_NODES) {
        const int v    = cnt[t];
        const int excl = scn[t] - v;
        const int node = b * BUCKET_NODES + t;
        if (node < N) {
            nodeInfo[node] = ((unsigned)v << 22) | (unsigned)(e0 + excl);
            dinv[node]     = rsqrtf((float)(v + 1));
        }
        cur[t] = e0 + excl;
    }
    __syncthreads();
    for (int e = e0 + t; e < e1; e += 1024) {
        unsigned int entry = bucketArr[e];
        int pos = atomicAdd(&cur[entry >> 24], 1);
        adj[pos] = entry & 0xFFFFFF;
    }
}

// ---- MFMA GEMM: out[M,NOUT] = A[M,K] @ W[K,NOUT] (+bias) -------------------
// Self-contained: W (fp32, [K][NOUT] input buffer) is split hi/lo fp16 and
// transposed into LDS by each block. No workspace-resident weight state.
// Block = 4 waves x 16 rows = 64 rows.
// A frag: lane l -> row (l&15), k = kst + (l>>4)*8 + i
// B frag: lane l -> col (l&15), same k, from LDS W^T[c][k] (hi/lo)
// D frag: lane l reg j -> row (l>>4)*4 + j, col (l&15)
// SCALE: multiply output row by dscale[row] before store (h' = h*dinv).
template <int K, int NOUT, int NCT, bool AHALF, bool OHALF, bool SCALE, bool BIAS>
__global__ __launch_bounds__(256) void gemm_mfma(const void* __restrict__ Av,
                                                 const float* __restrict__ W,
                                                 const float* __restrict__ bias,
                                                 const float* __restrict__ dscale,
                                                 void* __restrict__ outv, int M) {
    constexpr int KP = K + 8;                 // +16B row pad: 2-way bank floor
    __shared__ _Float16 WTh[64 * KP];
    __shared__ _Float16 WTl[64 * KP];

    for (int i = threadIdx.x; i < K * 64; i += 256) {
        int k = i >> 6, c = i & 63;
        float w = (NOUT == 64 || c < NOUT) ? W[k * NOUT + c] : 0.f;
        _Float16 h = (_Float16)w;
        WTh[c * KP + k] = h;
        WTl[c * KP + k] = (_Float16)(w - (float)h);
    }
    __syncthreads();

    const int lane = threadIdx.x & 63;
    const int wv   = threadIdx.x >> 6;
    const int r    = lane & 15;   // A-row / D-col within 16-tile
    const int q    = lane >> 4;   // k-group / D-row-group
    int arow = blockIdx.x * 64 + wv * 16 + r;
    if (arow > M - 1) arow = M - 1;

    f32x4 acc[NCT] = {};

#pragma unroll
    for (int kst = 0; kst < K; kst += 32) {
        half8 ah = {}, al = {};
        if (AHALF) {
            HV8 v;
            v.u = *(const uint4*)((const __half*)Av + (size_t)arow * K + kst + q * 8);
            ah = v.h;
        } else {
            const float* ap = (const float*)Av + (size_t)arow * K + kst + q * 8;
            float4 f0 = *(const float4*)ap;
            float4 f1 = *(const float4*)(ap + 4);
            float fs[8] = {f0.x, f0.y, f0.z, f0.w, f1.x, f1.y, f1.z, f1.w};
#pragma unroll
            for (int j = 0; j < 8; ++j) {
                _Float16 h = (_Float16)fs[j];
                ah[j] = h;
                al[j] = (_Float16)(fs[j] - (float)h);
            }
        }
#pragma unroll
        for (int n = 0; n < NCT; ++n) {
            const int bo = (n * 16 + r) * KP + kst + q * 8;
            HV8 bh, bl;
            bh.u = *(const uint4*)(WTh + bo);
            bl.u = *(const uint4*)(WTl + bo);
            acc[n] = __builtin_amdgcn_mfma_f32_16x16x32_f16(ah, bh.h, acc[n], 0, 0, 0);
            acc[n] = __builtin_amdgcn_mfma_f32_16x16x32_f16(ah, bl.h, acc[n], 0, 0, 0);
            if (!AHALF)
                acc[n] = __builtin_amdgcn_mfma_f32_16x16x32_f16(al, bh.h, acc[n], 0, 0, 0);
        }
    }

    const int orow0 = blockIdx.x * 64 + wv * 16 + q * 4;
#pragma unroll
    for (int n = 0; n < NCT; ++n) {
        const int col = n * 16 + r;
        float bb = 0.f;
        if (BIAS) bb = (col < NOUT) ? bias[col] : 0.f;
#pragma unroll
        for (int j = 0; j < 4; ++j) {
            const int row = orow0 + j;
            if (row >= M) break;
            const float sc = SCALE ? dscale[row] : 1.f;
            const float v = acc[n][j] * sc + bb;
            if (OHALF) {
                ((__half*)outv)[(size_t)row * NOUT + col] = __float2half(v);
            } else if (col < NOUT) {
                ((float*)outv)[(size_t)row * NOUT + col] = v;
            }
        }
    }
}

// Eighth-wave gather over pre-scaled h' rows (unweighted sum):
// out[i] = relu(dinv[i]*(h'[i] + sum_s h'[s]) + b)
// Batched MLP: per 8-edge block, 8 adj loads then 8 row loads then math.
__global__ __launch_bounds__(256) void gather_kernel(const __half* __restrict__ h,
                                                     const unsigned int* __restrict__ nodeInfo,
                                                     const unsigned int* __restrict__ adj,
                                                     const float* __restrict__ dinv,
                                                     const float* __restrict__ bias,
                                                     __half* __restrict__ out, int N) {
    const int node = blockIdx.x * 32 + (threadIdx.x >> 3);  // 32 nodes/block
    const int l    = threadIdx.x & 7;                       // lane within eighth
    if (node >= N) return;

    const unsigned info = nodeInfo[node];
    const int start = (int)(info & OFF_MASK);
    const int end   = start + (int)(info >> 22);
    const float di  = dinv[node];

    // self-loop term: h'[node] already carries one dinv factor
    float acc[8];
    {
        H8 sv;
        sv.u = *(const uint4*)(h + (size_t)node * 64 + l * 8);
#pragma unroll
        for (int k = 0; k < 8; ++k) acc[k] = __half2float(sv.h[k]);
    }

    for (int base = start; ; base += 8) {
        bool active = base < end;
        if (__ballot(active) == 0ull) break;
        const int m = active ? min(8, end - base) : 0;

        int s[8];
#pragma unroll
        for (int j = 0; j < 8; ++j) s[j] = (int)adj[base + j];  // bounded inside adj window

        uint4 rv[8];
#pragma unroll
        for (int j = 0; j < 8; ++j)
            if (j < m) rv[j] = *(const uint4*)(h + (size_t)s[j] * 64 + l * 8);

#pragma unroll
        for (int j = 0; j < 8; ++j)
            if (j < m) {
                H8 t;
                t.u = rv[j];
#pragma unroll
                for (int k = 0; k < 8; ++k) acc[k] += __half2float(t.h[k]);
            }
    }

    const float4 b0 = *(const float4*)(bias + l * 8);
    const float4 b1 = *(const float4*)(bias + l * 8 + 4);
    const float bb[8] = {b0.x, b0.y, b0.z, b0.w, b1.x, b1.y, b1.z, b1.w};
    H8 ov;
#pragma unroll
    for (int k = 0; k < 8; ++k) {
        float v = acc[k] * di + bb[k];
        ov.h[k] = __float2half(v > 0.f ? v : 0.f);
    }
    *(uint4*)(out + (size_t)node * 64 + l * 8) = ov.u;
}

extern "C" void kernel_launch(void* const* d_in, const int* in_sizes, int n_in,
                              void* d_out, int out_size, void* d_ws, size_t ws_size,
                              hipStream_t stream) {
    const float* x  = (const float*)d_in[0];
    const int*   ei = (const int*)d_in[1];
    const float* W1 = (const float*)d_in[2];
    const float* b1 = (const float*)d_in[3];
    const float* W2 = (const float*)d_in[4];
    const float* b2 = (const float*)d_in[5];
    const float* Wc = (const float*)d_in[6];
    const float* bc = (const float*)d_in[7];

    const int N = in_sizes[0] / 128;   // 100000
    const int E = in_sizes[1] / 2;     // 1000000
    const int* src = ei;
    const int* dst = ei + E;

    const int NB = (N + BUCKET_NODES - 1) >> BUCKET_BITS;   // 391
    const int EB = (E + 2047) / 2048;                        // 489

    char* w = (char*)d_ws;
    auto alloc = [&](size_t bytes) { char* p = w; w += (bytes + 255) & ~(size_t)255; return p; };
    int*          bucketCursor = (int*)alloc((size_t)NB * 4);
    unsigned int* bucketArr    = (unsigned int*)alloc((size_t)NB * CAP * 4);
    unsigned int* nodeInfo     = (unsigned int*)alloc((size_t)N * 4);
    unsigned int* adj          = (unsigned int*)alloc((size_t)NB * CAP * 4);
    float*        dinv         = (float*)alloc((size_t)N * 4);
    __half*       bufA         = (__half*)alloc((size_t)N * 64 * 2);
    __half*       bufB         = (__half*)alloc((size_t)N * 64 * 2);

    dim3 blk(256);
    const int nblkG = (N + 63) / 64;   // 64 rows per block
    const int nblkV = (N + 31) / 32;   // eighth-wave gather: 32 nodes/block

    // ---- bucket build (3 launches) ----
    zero_kernel<<<(NB + 255) / 256, blk, 0, stream>>>(bucketCursor, NB);
    bucket_fill_kernel<<<EB, blk, 0, stream>>>(src, dst, bucketCursor, bucketArr, E, NB);
    node_sort_kernel<<<NB, dim3(1024), 0, stream>>>(bucketArr, bucketCursor, nodeInfo, dinv, adj, N);

    // ---- layer 1:  bufA = (x @ W1) * dinv[row]  ->  gather -> bufB ----
    gemm_mfma<128, 64, 4, false, true, true, false><<<nblkG, blk, 0, stream>>>(
        x, W1, nullptr, dinv, bufA, N);
    gather_kernel<<<nblkV, blk, 0, stream>>>(bufA, nodeInfo, adj, dinv, b1, bufB, N);

    // ---- layer 2 ----
    gemm_mfma<64, 64, 4, true, true, true, false><<<nblkG, blk, 0, stream>>>(
        bufB, W2, nullptr, dinv, bufA, N);
    gather_kernel<<<nblkV, blk, 0, stream>>>(bufA, nodeInfo, adj, dinv, b2, bufB, N);

    // ---- head ----
    gemm_mfma<64, 40, 3, true, false, false, true><<<nblkG, blk, 0, stream>>>(
        bufB, Wc, bc, nullptr, d_out, N);
}